// Round 5
// baseline (6402.335 us; speedup 1.0000x reference)
//
#include <hip/hip_runtime.h>
#include <stdint.h>
#include <math.h>

#define B_N 8192
#define F_N 2048
#define K_N 256
#define L_N 10
#define SIGMA_F 1.0f
#define PSCALE (1.0f/16384.0f)
#define SC2 (PSCALE*PSCALE)

#define FMA16(acc, a, b) \
  acc[0][0] += a.x*b.x; acc[0][1] += a.x*b.y; acc[0][2] += a.x*b.z; acc[0][3] += a.x*b.w; \
  acc[1][0] += a.y*b.x; acc[1][1] += a.y*b.y; acc[1][2] += a.y*b.z; acc[1][3] += a.y*b.w; \
  acc[2][0] += a.z*b.x; acc[2][1] += a.z*b.y; acc[2][2] += a.z*b.z; acc[2][3] += a.z*b.w; \
  acc[3][0] += a.w*b.x; acc[3][1] += a.w*b.y; acc[3][2] += a.w*b.z; acc[3][3] += a.w*b.w;

__device__ __forceinline__ float hashf(uint32_t x) {
  x ^= x >> 17; x *= 0xed5ad4bbu; x ^= x >> 11; x *= 0xac4c1b51u;
  x ^= x >> 15; x *= 0x31848babu; x ^= x >> 14;
  return ((float)(x >> 8)) * 1.1920929e-7f - 1.0f;
}

// ---------------- seed random start block ----------------
__global__ void seed_kernel(float* __restrict__ Y) {
  uint32_t i = blockIdx.x * 256 + threadIdx.x;
  Y[i] = hashf(i * 2654435761u + 777u);
}

// ---------------- column sums of X ----------------
__global__ void colsum_kernel(const float* __restrict__ X, float* __restrict__ s) {
  int col = blockIdx.x * 256 + threadIdx.x;
  int r0 = blockIdx.y * 256;
  float acc = 0.0f;
  for (int r = 0; r < 256; ++r) acc += X[(size_t)(r0 + r) * F_N + col];
  atomicAdd(&s[col], acc);
}

// ---------------- C = X^T X - s s^T / B  (symmetric: lower blocks + mirror) ----------------
__global__ __launch_bounds__(256) void syrk_kernel(const float* __restrict__ X,
    const float* __restrict__ s, float* __restrict__ C) {
  if (blockIdx.y > blockIdx.x) return;   // symmetric: compute lower block-triangle only
  __shared__ float As[16][64];
  __shared__ float Bs[16][64];
  const int I = blockIdx.x * 64, J = blockIdx.y * 64;
  const int tid = threadIdx.x;
  const int tx = tid & 15, ty = tid >> 4;
  float acc[4][4] = {};
  for (int kb = 0; kb < B_N; kb += 16) {
    const float4 va = *(const float4*)(&X[(size_t)(kb + ty) * F_N + I + tx * 4]);
    const float4 vb = *(const float4*)(&X[(size_t)(kb + ty) * F_N + J + tx * 4]);
    __syncthreads();
    *(float4*)(&As[ty][tx * 4]) = va;
    *(float4*)(&Bs[ty][tx * 4]) = vb;
    __syncthreads();
#pragma unroll
    for (int kk = 0; kk < 16; ++kk) {
      const float4 a = *(const float4*)(&As[kk][ty * 4]);
      const float4 b = *(const float4*)(&Bs[kk][tx * 4]);
      FMA16(acc, a, b)
    }
  }
  const float invB = 1.0f / (float)B_N;
  const bool mirror = (blockIdx.x != blockIdx.y);
#pragma unroll
  for (int u = 0; u < 4; ++u) {
    int gi = I + ty * 4 + u;
    float su = s[gi] * invB;
#pragma unroll
    for (int v = 0; v < 4; ++v) {
      int gj = J + tx * 4 + v;
      float val = acc[u][v] - su * s[gj];
      C[(size_t)gi * F_N + gj] = val;
      if (mirror) C[(size_t)gj * F_N + gi] = val;
    }
  }
}

// ---------------- D = scale * A * A^T  (A symmetric-use; lower blocks + mirror) ----------------
// FIX R4: LDS tiles were [32][36] but staging writes column index lr=tid>>2 in 0..63
// -> OOB LDS writes + reads of unwritten LDS -> garbage C2/C4 -> Inf -> NaN. Now [32][68].
__global__ __launch_bounds__(256) void gemm_nt_kernel(const float* __restrict__ A,
    const float* __restrict__ B, float* __restrict__ D, float scale) {
  if (blockIdx.y > blockIdx.x) return;
  __shared__ float As[32][68];
  __shared__ float Bs[32][68];
  const int I = blockIdx.x * 64, J = blockIdx.y * 64;
  const int tid = threadIdx.x;
  const int tx = tid & 15, ty = tid >> 4;
  const int lr = tid >> 2, ls = (tid & 3) * 4;
  float acc[4][4] = {};
  for (int kb = 0; kb < F_N; kb += 32) {
    const float4 a0 = *(const float4*)(&A[(size_t)(I + lr) * F_N + kb + ls]);
    const float4 a1 = *(const float4*)(&A[(size_t)(I + lr) * F_N + kb + 16 + ls]);
    const float4 b0 = *(const float4*)(&B[(size_t)(J + lr) * F_N + kb + ls]);
    const float4 b1 = *(const float4*)(&B[(size_t)(J + lr) * F_N + kb + 16 + ls]);
    __syncthreads();
    As[ls + 0][lr] = a0.x; As[ls + 1][lr] = a0.y; As[ls + 2][lr] = a0.z; As[ls + 3][lr] = a0.w;
    As[16 + ls + 0][lr] = a1.x; As[16 + ls + 1][lr] = a1.y; As[16 + ls + 2][lr] = a1.z; As[16 + ls + 3][lr] = a1.w;
    Bs[ls + 0][lr] = b0.x; Bs[ls + 1][lr] = b0.y; Bs[ls + 2][lr] = b0.z; Bs[ls + 3][lr] = b0.w;
    Bs[16 + ls + 0][lr] = b1.x; Bs[16 + ls + 1][lr] = b1.y; Bs[16 + ls + 2][lr] = b1.z; Bs[16 + ls + 3][lr] = b1.w;
    __syncthreads();
#pragma unroll
    for (int kk = 0; kk < 32; ++kk) {
      const float4 a = *(const float4*)(&As[kk][ty * 4]);
      const float4 b = *(const float4*)(&Bs[kk][tx * 4]);
      FMA16(acc, a, b)
    }
  }
  const bool mirror = (blockIdx.x != blockIdx.y);
#pragma unroll
  for (int u = 0; u < 4; ++u)
#pragma unroll
    for (int v = 0; v < 4; ++v) {
      float val = acc[u][v] * scale;
      D[(size_t)(I + ty * 4 + u) * F_N + J + tx * 4 + v] = val;
      if (mirror) D[(size_t)(J + tx * 4 + v) * F_N + I + ty * 4 + u] = val;
    }
}

// ---------------- Yout += M * Yin (M: 2048x2048; 64x64 tiles, split-K z=4) ----------------
__global__ __launch_bounds__(256) void powgemm_kernel(const float* __restrict__ M,
    const float* __restrict__ Yin, float* __restrict__ Yout) {
  __shared__ float Ast[32][68];
  __shared__ float Bs[32][64];
  const int I = blockIdx.x * 64, J = blockIdx.y * 64;
  const int kbase = blockIdx.z * (F_N / 4);
  const int tid = threadIdx.x;
  const int tx = tid & 15, ty = tid >> 4;
  float acc[4][4] = {};
  for (int kb = 0; kb < F_N / 4; kb += 32) {
    int r = tid >> 2, cb = (tid & 3) * 8;
    const float4 a0 = *(const float4*)(&M[(size_t)(I + r) * F_N + kbase + kb + cb]);
    const float4 a1 = *(const float4*)(&M[(size_t)(I + r) * F_N + kbase + kb + cb + 4]);
    const float4 bv0 = *(const float4*)(&Yin[(size_t)(kbase + kb + (tid >> 4)) * K_N + J + (tid & 15) * 4]);
    const float4 bv1 = *(const float4*)(&Yin[(size_t)(kbase + kb + (tid >> 4) + 16) * K_N + J + (tid & 15) * 4]);
    __syncthreads();
    Ast[cb + 0][r] = a0.x; Ast[cb + 1][r] = a0.y; Ast[cb + 2][r] = a0.z; Ast[cb + 3][r] = a0.w;
    Ast[cb + 4][r] = a1.x; Ast[cb + 5][r] = a1.y; Ast[cb + 6][r] = a1.z; Ast[cb + 7][r] = a1.w;
    *(float4*)(&Bs[tid >> 4][(tid & 15) * 4]) = bv0;
    *(float4*)(&Bs[(tid >> 4) + 16][(tid & 15) * 4]) = bv1;
    __syncthreads();
#pragma unroll
    for (int kk = 0; kk < 32; ++kk) {
      const float4 a = *(const float4*)(&Ast[kk][ty * 4]);
      const float4 b = *(const float4*)(&Bs[kk][tx * 4]);
      FMA16(acc, a, b)
    }
  }
#pragma unroll
  for (int u = 0; u < 4; ++u)
#pragma unroll
    for (int v = 0; v < 4; ++v)
      atomicAdd(&Yout[(size_t)(I + ty * 4 + u) * K_N + J + tx * 4 + v], acc[u][v]);
}

// ---------------- G += Y^T Y (split-K over z) ----------------
__global__ __launch_bounds__(256) void gram_kernel(const float* __restrict__ Y, float* __restrict__ G) {
  __shared__ float As[16][64];
  __shared__ float Bs[16][64];
  const int I = blockIdx.x * 64, J = blockIdx.y * 64;
  const int k0 = blockIdx.z * (F_N / 8);
  const int tid = threadIdx.x;
  const int tx = tid & 15, ty = tid >> 4;
  float acc[4][4] = {};
  for (int kb = 0; kb < F_N / 8; kb += 16) {
    const float4 va = *(const float4*)(&Y[(size_t)(k0 + kb + ty) * K_N + I + tx * 4]);
    const float4 vb = *(const float4*)(&Y[(size_t)(k0 + kb + ty) * K_N + J + tx * 4]);
    __syncthreads();
    *(float4*)(&As[ty][tx * 4]) = va;
    *(float4*)(&Bs[ty][tx * 4]) = vb;
    __syncthreads();
#pragma unroll
    for (int kk = 0; kk < 16; ++kk) {
      const float4 a = *(const float4*)(&As[kk][ty * 4]);
      const float4 b = *(const float4*)(&Bs[kk][tx * 4]);
      FMA16(acc, a, b)
    }
  }
#pragma unroll
  for (int u = 0; u < 4; ++u)
#pragma unroll
    for (int v = 0; v < 4; ++v)
      atomicAdd(&G[(size_t)(I + ty * 4 + u) * K_N + J + tx * 4 + v], acc[u][v]);
}

// ---------------- batched 256x256 Cholesky in packed LDS: L, 1/diag, logdet ----------------
__global__ __launch_bounds__(256) void chol_kernel(const float* __restrict__ Ain,
    float* __restrict__ Lout, float* __restrict__ invdout, float* __restrict__ logdet) {
  const int b = blockIdx.x;
  const float* A = Ain + (size_t)b * K_N * K_N;
  float* L = Lout + (size_t)b * K_N * K_N;
  const int tid = threadIdx.x;
  const int rb = (tid * (tid + 1)) >> 1;
  __shared__ float T[(K_N * (K_N + 1)) / 2];   // 131.5 KB packed lower (gfx950: 160 KB/WG)
  __shared__ float col[K_N];
  __shared__ float sh_invd, sh_ld;
  for (int i = 0; i < K_N; ++i)
    if (tid <= i) T[((i * (i + 1)) >> 1) + tid] = A[(size_t)i * K_N + tid];
  if (tid == 0) sh_ld = 0.f;
  __syncthreads();
  for (int j = 0; j < K_N; ++j) {
    if (tid == 0) {
      float d = sqrtf(fmaxf(T[((j * (j + 1)) >> 1) + j], 1e-20f));
      T[((j * (j + 1)) >> 1) + j] = d;
      sh_invd = 1.0f / d;
      sh_ld += logf(d);
    }
    __syncthreads();
    float c = 0.f;
    if (tid > j) { c = T[rb + j] * sh_invd; T[rb + j] = c; }
    col[tid] = c;
    __syncthreads();
    if (tid > j) {
      float* Trow = T + rb;
      for (int k = j + 1; k <= tid; ++k) Trow[k] -= c * col[k];
    }
    __syncthreads();
  }
  if (tid == 0) logdet[b] = 2.0f * sh_ld;
  invdout[(size_t)b * K_N + tid] = 1.0f / T[rb + tid];
  for (int i = 0; i < K_N; ++i)
    if (tid <= i) L[(size_t)i * K_N + tid] = T[((i * (i + 1)) >> 1) + tid];
}

// ---------------- wave-per-row TRSM: Yout * L^T = Yin  (Q = Y L^{-T}) ----------------
__global__ __launch_bounds__(256) void trsm_rows_kernel(const float* __restrict__ L,
    const float* __restrict__ invd, const float* __restrict__ Yin, float* __restrict__ Yout) {
  const int w = threadIdx.x >> 6, lane = threadIdx.x & 63;
  const int row = blockIdx.x * 4 + w;
  float yv[4];
#pragma unroll
  for (int m = 0; m < 4; ++m) yv[m] = Yin[(size_t)row * K_N + lane + 64 * m];
#pragma unroll
  for (int m = 0; m < 4; ++m) {
    for (int cc = 0; cc < 64; ++cc) {
      const int c = m * 64 + cc;
      const float* Lrow = L + (size_t)c * K_N;
      float yc = __shfl(yv[m], cc);
      float part = 0.f;
#pragma unroll
      for (int mm = 0; mm < m; ++mm) part += yv[mm] * Lrow[lane + 64 * mm];
      if (lane < cc) part += yv[m] * Lrow[lane + 64 * m];
#pragma unroll
      for (int off = 1; off < 64; off <<= 1) part += __shfl_xor(part, off);
      float val = (yc - part) * invd[c];
      if (lane == cc) yv[m] = val;
    }
  }
#pragma unroll
  for (int m = 0; m < 4; ++m) Yout[(size_t)row * K_N + lane + 64 * m] = yv[m];
}

// ---------------- wave-per-column solve L W = I; writes W^T ----------------
__global__ __launch_bounds__(256) void trsm_winv_kernel(const float* __restrict__ Lall,
    const float* __restrict__ invdall, float* __restrict__ Wt) {
  const int w = threadIdx.x >> 6, lane = threadIdx.x & 63;
  const int gw = blockIdx.x * 4 + w;
  const int b = gw >> 8, j = gw & 255;
  const float* L = Lall + (size_t)b * K_N * K_N;
  const float* invd = invdall + (size_t)b * K_N;
  float yv[4];
#pragma unroll
  for (int m = 0; m < 4; ++m) yv[m] = 0.f;
#pragma unroll
  for (int m = 0; m < 4; ++m) {
    for (int cc = 0; cc < 64; ++cc) {
      const int c = m * 64 + cc;
      const float* Lrow = L + (size_t)c * K_N;
      float part = 0.f;
#pragma unroll
      for (int mm = 0; mm < m; ++mm) part += yv[mm] * Lrow[lane + 64 * mm];
      if (lane < cc) part += yv[m] * Lrow[lane + 64 * m];
#pragma unroll
      for (int off = 1; off < 64; off <<= 1) part += __shfl_xor(part, off);
      float val = (((c == j) ? 1.0f : 0.0f) - part) * invd[c];
      if (lane == cc) yv[m] = val;
    }
  }
#pragma unroll
  for (int m = 0; m < 4; ++m) Wt[((size_t)b * K_N + j) * K_N + lane + 64 * m] = yv[m];
}

// ---------------- mproj[j] += (1/B) * sum_f s[f] Y[f][j] ----------------
__global__ void meanproj_kernel(const float* __restrict__ s, const float* __restrict__ Y,
                                float* __restrict__ mproj) {
  int j = threadIdx.x;
  int f0 = blockIdx.x * 256;
  float acc = 0.0f;
  for (int f = 0; f < 256; ++f) acc += s[f0 + f] * Y[(size_t)(f0 + f) * K_N + j];
  atomicAdd(&mproj[j], acc * (1.0f / (float)B_N));
}

// ---------------- P = X * Y - 1*mproj^T ----------------
__global__ __launch_bounds__(256) void proj_kernel(const float* __restrict__ X,
    const float* __restrict__ Y, const float* __restrict__ mproj, float* __restrict__ P) {
  __shared__ float Ast[32][68];
  __shared__ float Bs[32][64];
  const int I = blockIdx.x * 64, J = blockIdx.y * 64;
  const int tid = threadIdx.x;
  const int tx = tid & 15, ty = tid >> 4;
  float acc[4][4] = {};
  for (int kb = 0; kb < F_N; kb += 32) {
    {
      int r = tid >> 2, cb = (tid & 3) * 8;
      const float4 a0 = *(const float4*)(&X[(size_t)(I + r) * F_N + kb + cb]);
      const float4 a1 = *(const float4*)(&X[(size_t)(I + r) * F_N + kb + cb + 4]);
      const float4 bv0 = *(const float4*)(&Y[(size_t)(kb + (tid >> 4)) * K_N + J + (tid & 15) * 4]);
      const float4 bv1 = *(const float4*)(&Y[(size_t)(kb + (tid >> 4) + 16) * K_N + J + (tid & 15) * 4]);
      __syncthreads();
      Ast[cb + 0][r] = a0.x; Ast[cb + 1][r] = a0.y; Ast[cb + 2][r] = a0.z; Ast[cb + 3][r] = a0.w;
      Ast[cb + 4][r] = a1.x; Ast[cb + 5][r] = a1.y; Ast[cb + 6][r] = a1.z; Ast[cb + 7][r] = a1.w;
      *(float4*)(&Bs[tid >> 4][(tid & 15) * 4]) = bv0;
      *(float4*)(&Bs[(tid >> 4) + 16][(tid & 15) * 4]) = bv1;
    }
    __syncthreads();
#pragma unroll
    for (int kk = 0; kk < 32; ++kk) {
      const float4 a = *(const float4*)(&Ast[kk][ty * 4]);
      const float4 b = *(const float4*)(&Bs[kk][tx * 4]);
      FMA16(acc, a, b)
    }
  }
#pragma unroll
  for (int u = 0; u < 4; ++u) {
    int gi = I + ty * 4 + u;
#pragma unroll
    for (int v = 0; v < 4; ++v) {
      int gj = J + tx * 4 + v;
      P[(size_t)gi * K_N + gj] = acc[u][v] - mproj[gj];
    }
  }
}

// ---------------- label histogram ----------------
__global__ void counts_kernel(const int* __restrict__ labels, int* __restrict__ counts) {
  __shared__ int c[L_N];
  int tid = threadIdx.x;
  if (tid < L_N) c[tid] = 0;
  __syncthreads();
  int lab = labels[blockIdx.x * 256 + tid];
  atomicAdd(&c[lab], 1);
  __syncthreads();
  if (tid < L_N) atomicAdd(&counts[tid], c[tid]);
}

// ---------------- per-label column sums of P ----------------
__global__ void musum_kernel(const int* __restrict__ labels, const float* __restrict__ P,
                             float* __restrict__ musum) {
  __shared__ float m[L_N][K_N];
  int tid = threadIdx.x;
#pragma unroll
  for (int l = 0; l < L_N; ++l) m[l][tid] = 0.0f;
  __syncthreads();
  int base = blockIdx.x * 256;
  for (int r = 0; r < 256; ++r) {
    int lab = labels[base + r];
    m[lab][tid] += P[(size_t)(base + r) * K_N + tid];
  }
  __syncthreads();
#pragma unroll
  for (int l = 0; l < L_N; ++l) atomicAdd(&musum[l * K_N + tid], m[l][tid]);
}

// ---------------- compact per-label row index lists (deterministic order) ----------------
__global__ void compact_kernel(const int* __restrict__ labels, int* __restrict__ idx) {
  const int l = blockIdx.x;
  const int tid = threadIdx.x;
  __shared__ int sc[256];
  __shared__ int s_off;
  if (tid == 0) s_off = 0;
  __syncthreads();
  for (int base = 0; base < B_N; base += 256) {
    int match = (labels[base + tid] == l) ? 1 : 0;
    sc[tid] = match;
    __syncthreads();
    for (int st = 1; st < 256; st <<= 1) {
      int v = (tid >= st) ? sc[tid - st] : 0;
      __syncthreads();
      sc[tid] += v;
      __syncthreads();
    }
    if (match) idx[l * 2048 + s_off + sc[tid] - 1] = base + tid;
    __syncthreads();
    if (tid == 0) s_off += sc[255];
    __syncthreads();
  }
}

// ---------------- per-label scatter S_l = sum_{i in l} x_i x_i^T (symmetric) ----------------
__global__ __launch_bounds__(256) void scatter_kernel(const float* __restrict__ P,
    const int* __restrict__ idx, const int* __restrict__ counts, float* __restrict__ S) {
  const int Ib = blockIdx.y >> 2, Jb = blockIdx.y & 3;
  if (Jb > Ib) return;   // symmetric: lower block-triangle only
  __shared__ float As[32][64];
  __shared__ float Bs[32][64];
  const int l = blockIdx.x;
  const int I = Ib * 64, J = Jb * 64;
  const int cnt = counts[l];
  const int tid = threadIdx.x;
  const int tx = tid & 15, ty = tid >> 4;
  float acc[4][4] = {};
  for (int chunk = 0; chunk < cnt; chunk += 32) {
#pragma unroll
    for (int e = 0; e < 2; ++e) {
      int r = (tid >> 4) + e * 16;
      int rr = chunk + r;
      float4 va = {0.f, 0.f, 0.f, 0.f}, vb = {0.f, 0.f, 0.f, 0.f};
      if (rr < cnt) {
        int row = idx[l * 2048 + rr];
        va = *(const float4*)(&P[(size_t)row * K_N + I + (tid & 15) * 4]);
        vb = *(const float4*)(&P[(size_t)row * K_N + J + (tid & 15) * 4]);
      }
      __syncthreads();
      *(float4*)(&As[r][(tid & 15) * 4]) = va;
      *(float4*)(&Bs[r][(tid & 15) * 4]) = vb;
    }
    __syncthreads();
#pragma unroll
    for (int kk = 0; kk < 32; ++kk) {
      const float4 a = *(const float4*)(&As[kk][ty * 4]);
      const float4 b = *(const float4*)(&Bs[kk][tx * 4]);
      FMA16(acc, a, b)
    }
  }
  const bool mirror = (Ib != Jb);
#pragma unroll
  for (int u = 0; u < 4; ++u)
#pragma unroll
    for (int v = 0; v < 4; ++v) {
      S[((size_t)l * K_N + I + ty * 4 + u) * K_N + J + tx * 4 + v] = acc[u][v];
      if (mirror) S[((size_t)l * K_N + J + tx * 4 + v) * K_N + I + ty * 4 + u] = acc[u][v];
    }
}

// ---------------- sig = S/c - mu mu^T + sigma*I ; copy for cholesky ----------------
__global__ void sigbuild_kernel(float* __restrict__ S, float* __restrict__ CH,
    const float* __restrict__ musum, const int* __restrict__ counts) {
  const int l = blockIdx.x, i = blockIdx.y, j = threadIdx.x;
  const float cf = fmaxf((float)counts[l], 1.0f);
  const float inv = 1.0f / cf;
  const float mui = musum[l * K_N + i] * inv;
  const float muj = musum[l * K_N + j] * inv;
  size_t o = ((size_t)l * K_N + i) * K_N + j;
  float v = S[o] * inv - mui * muj + ((i == j) ? SIGMA_F : 0.0f);
  S[o] = v;
  CH[o] = v;
}

// ---------------- Sinv = W^T W from Wt rows (NT product, symmetric) ----------------
// FIX R4: same [32][36] -> [32][68] LDS overflow fix as gemm_nt_kernel.
__global__ __launch_bounds__(256) void sinv_nt_kernel(const float* __restrict__ Wt, float* __restrict__ V) {
  if (blockIdx.y > blockIdx.x) return;
  __shared__ float As[32][68];
  __shared__ float Bs[32][68];
  const int b = blockIdx.z;
  const float* Wb = Wt + (size_t)b * K_N * K_N;
  const int I = blockIdx.x * 64, J = blockIdx.y * 64;
  const int tid = threadIdx.x;
  const int tx = tid & 15, ty = tid >> 4;
  const int lr = tid >> 2, ls = (tid & 3) * 4;
  float acc[4][4] = {};
  for (int kb = 0; kb < K_N; kb += 32) {
    const float4 a0 = *(const float4*)(&Wb[(size_t)(I + lr) * K_N + kb + ls]);
    const float4 a1 = *(const float4*)(&Wb[(size_t)(I + lr) * K_N + kb + 16 + ls]);
    const float4 b0 = *(const float4*)(&Wb[(size_t)(J + lr) * K_N + kb + ls]);
    const float4 b1 = *(const float4*)(&Wb[(size_t)(J + lr) * K_N + kb + 16 + ls]);
    __syncthreads();
    As[ls + 0][lr] = a0.x; As[ls + 1][lr] = a0.y; As[ls + 2][lr] = a0.z; As[ls + 3][lr] = a0.w;
    As[16 + ls + 0][lr] = a1.x; As[16 + ls + 1][lr] = a1.y; As[16 + ls + 2][lr] = a1.z; As[16 + ls + 3][lr] = a1.w;
    Bs[ls + 0][lr] = b0.x; Bs[ls + 1][lr] = b0.y; Bs[ls + 2][lr] = b0.z; Bs[ls + 3][lr] = b0.w;
    Bs[16 + ls + 0][lr] = b1.x; Bs[16 + ls + 1][lr] = b1.y; Bs[16 + ls + 2][lr] = b1.z; Bs[16 + ls + 3][lr] = b1.w;
    __syncthreads();
#pragma unroll
    for (int kk = 0; kk < 32; ++kk) {
      const float4 a = *(const float4*)(&As[kk][ty * 4]);
      const float4 b = *(const float4*)(&Bs[kk][tx * 4]);
      FMA16(acc, a, b)
    }
  }
  const bool mirror = (blockIdx.x != blockIdx.y);
#pragma unroll
  for (int u = 0; u < 4; ++u)
#pragma unroll
    for (int v = 0; v < 4; ++v) {
      V[((size_t)b * K_N + I + ty * 4 + u) * K_N + J + tx * 4 + v] = acc[u][v];
      if (mirror) V[((size_t)b * K_N + J + tx * 4 + v) * K_N + I + ty * 4 + u] = acc[u][v];
    }
}

// ---------------- pairwise weighted KL terms ----------------
__global__ void klpairs_kernel(const float* __restrict__ SIG, const float* __restrict__ SINV,
    const float* __restrict__ musum, const int* __restrict__ counts,
    const float* __restrict__ logdet, float* __restrict__ klbuf) {
  const int j = blockIdx.x, i = blockIdx.y;
  const int tid = threadIdx.x;
  if (i == j) { if (tid == 0) klbuf[i * L_N + j] = 0.0f; return; }
  const float* Si = SIG + (size_t)i * K_N * K_N;
  const float* Vj = SINV + (size_t)j * K_N * K_N;
  const float ci = fmaxf((float)counts[i], 1.0f);
  const float cj = fmaxf((float)counts[j], 1.0f);
  __shared__ float diff[K_N];
  diff[tid] = musum[i * K_N + tid] / ci - musum[j * K_N + tid] / cj;
  float tr = 0.0f;
  for (int e = tid; e < K_N * K_N; e += 256) tr += Vj[e] * Si[e];
  __syncthreads();
  float tmp = 0.0f;
  for (int b2 = 0; b2 < K_N; ++b2) tmp += Vj[(size_t)b2 * K_N + tid] * diff[b2];
  float mah = tmp * diff[tid];
  __shared__ float red[256];
  red[tid] = tr + mah;
  __syncthreads();
  for (int st = 128; st > 0; st >>= 1) {
    if (tid < st) red[tid] += red[tid + st];
    __syncthreads();
  }
  if (tid == 0) {
    float kl = 0.5f * (logdet[j] - logdet[i] - (float)K_N + red[0]);
    klbuf[i * L_N + j] = (float)counts[i] * (float)counts[j] * kl;
  }
}

// ---------------- final reduce ----------------
__global__ void final_kernel(const float* __restrict__ klbuf, float* __restrict__ out) {
  __shared__ float red[128];
  int tid = threadIdx.x;
  red[tid] = (tid < L_N * L_N) ? klbuf[tid] : 0.0f;
  __syncthreads();
  for (int st = 64; st > 0; st >>= 1) {
    if (tid < st) red[tid] += red[tid + st];
    __syncthreads();
  }
  if (tid == 0) out[0] = red[0] / 5.49755813888e11f;
}

extern "C" void kernel_launch(void* const* d_in, const int* in_sizes, int n_in,
                              void* d_out, int out_size, void* d_ws, size_t ws_size,
                              hipStream_t stream) {
  (void)in_sizes; (void)n_in; (void)out_size; (void)ws_size;
  const float* X = (const float*)d_in[0];
  const int* labels = (const int*)d_in[1];
  float* out = (float*)d_out;

  float* w = (float*)d_ws;
  size_t off = 0;
  auto alloc = [&](size_t n) { float* p = w + off; off += (n + 63) & ~(size_t)63; return p; };
  float* C    = alloc((size_t)F_N * F_N);      // later reused as C4
  float* C2   = alloc((size_t)F_N * F_N);
  float* Y0   = alloc((size_t)F_N * K_N);
  float* Y1   = alloc((size_t)F_N * K_N);
  float* P    = alloc((size_t)B_N * K_N);
  float* S    = alloc((size_t)L_N * K_N * K_N);
  float* CH   = alloc((size_t)L_N * K_N * K_N); // later reused as SINV
  float* LL   = alloc((size_t)L_N * K_N * K_N);
  float* Wt   = alloc((size_t)L_N * K_N * K_N);
  float* G2   = alloc((size_t)K_N * K_N);
  float* LQ   = alloc((size_t)K_N * K_N);
  float* svec = alloc(F_N);
  float* mproj = alloc(K_N);
  float* musum = alloc(L_N * K_N);
  float* logdet = alloc(64);
  float* klbuf = alloc(128);
  float* ldq = alloc(64);
  float* invdQ = alloc(K_N);
  float* invdL = alloc(L_N * K_N);
  int* counts = (int*)alloc(64);
  int* idx = (int*)alloc(L_N * 2048);
  float* C4 = C;      // alias: C dead after C2 built
  float* SINV = CH;   // alias: CH dead after chol consumed

  hipMemsetAsync(svec, 0, F_N * 4, stream);
  hipMemsetAsync(counts, 0, 64 * 4, stream);
  hipMemsetAsync(musum, 0, L_N * K_N * 4, stream);
  hipMemsetAsync(mproj, 0, K_N * 4, stream);

  colsum_kernel<<<dim3(F_N / 256, B_N / 256), 256, 0, stream>>>(X, svec);
  syrk_kernel<<<dim3(F_N / 64, F_N / 64), 256, 0, stream>>>(X, svec, C);
  // C2 = (C*C^T)*s^2 ; C4 = C2*C2^T (into C's buffer) -> one C4 apply == 4 scaled lambda-steps
  gemm_nt_kernel<<<dim3(F_N / 64, F_N / 64), 256, 0, stream>>>(C, C, C2, (float)SC2);
  gemm_nt_kernel<<<dim3(F_N / 64, F_N / 64), 256, 0, stream>>>(C2, C2, C4, 1.0f);
  seed_kernel<<<(F_N * K_N) / 256, 256, 0, stream>>>(Y0);

  float* Yc = Y0; float* Yn = Y1;
  auto do_apply = [&](const float* M) {
    hipMemsetAsync(Yn, 0, (size_t)F_N * K_N * 4, stream);
    powgemm_kernel<<<dim3(F_N / 64, K_N / 64, 4), 256, 0, stream>>>(M, Yc, Yn);
    float* t = Yc; Yc = Yn; Yn = t;
  };
  auto do_qr = [&]() {
    hipMemsetAsync(G2, 0, (size_t)K_N * K_N * 4, stream);
    gram_kernel<<<dim3(4, 4, 8), 256, 0, stream>>>(Yc, G2);
    chol_kernel<<<1, 256, 0, stream>>>(G2, LQ, invdQ, ldq);
    trsm_rows_kernel<<<F_N / 4, 256, 0, stream>>>(LQ, invdQ, Yc, Yn);
    float* t = Yc; Yc = Yn; Yn = t;
  };

  // lambda^42 = C4 x10 + C2 x1. Orths at t=4, 24, 42 (+polish = CholQR2).
  // Max gap 20 lambda-steps: Gram cond ~ (2.25/1.7)^40 ~ 9e4 -> fp32-safe.
  do_apply(C4);                                 // t=4
  do_qr();
  for (int a = 0; a < 5; ++a) do_apply(C4);     // t=24
  do_qr();
  for (int a = 0; a < 4; ++a) do_apply(C4);     // t=40
  do_apply(C2);                                 // t=42
  do_qr();
  do_qr();                                      // polish: orthonormal to fp32 eps

  meanproj_kernel<<<F_N / 256, 256, 0, stream>>>(svec, Yc, mproj);
  proj_kernel<<<dim3(B_N / 64, K_N / 64), 256, 0, stream>>>(X, Yc, mproj, P);
  counts_kernel<<<B_N / 256, 256, 0, stream>>>(labels, counts);
  musum_kernel<<<B_N / 256, 256, 0, stream>>>(labels, P, musum);
  compact_kernel<<<L_N, 256, 0, stream>>>(labels, idx);
  scatter_kernel<<<dim3(L_N, 16), 256, 0, stream>>>(P, idx, counts, S);
  sigbuild_kernel<<<dim3(L_N, K_N), 256, 0, stream>>>(S, CH, musum, counts);
  chol_kernel<<<L_N, 256, 0, stream>>>(CH, LL, invdL, logdet);
  trsm_winv_kernel<<<(L_N * K_N) / 4, 256, 0, stream>>>(LL, invdL, Wt);
  sinv_nt_kernel<<<dim3(4, 4, L_N), 256, 0, stream>>>(Wt, SINV);
  klpairs_kernel<<<dim3(L_N, L_N), 256, 0, stream>>>(S, SINV, musum, counts, logdet, klbuf);
  final_kernel<<<1, 128, 0, stream>>>(klbuf, out);
}

// Round 7
// 4845.436 us; speedup vs baseline: 1.3213x; 1.3213x over previous
//
#include <hip/hip_runtime.h>
#include <stdint.h>
#include <math.h>

#define B_N 8192
#define F_N 2048
#define K_N 256
#define L_N 10
#define SIGMA_F 1.0f
#define PSCALE (1.0f/16384.0f)
#define SC2 (PSCALE*PSCALE)
#define NB 8

#define FMA16(acc, a, b) \
  acc[0][0] += a.x*b.x; acc[0][1] += a.x*b.y; acc[0][2] += a.x*b.z; acc[0][3] += a.x*b.w; \
  acc[1][0] += a.y*b.x; acc[1][1] += a.y*b.y; acc[1][2] += a.y*b.z; acc[1][3] += a.y*b.w; \
  acc[2][0] += a.z*b.x; acc[2][1] += a.z*b.y; acc[2][2] += a.z*b.z; acc[2][3] += a.z*b.w; \
  acc[3][0] += a.w*b.x; acc[3][1] += a.w*b.y; acc[3][2] += a.w*b.z; acc[3][3] += a.w*b.w;

__device__ __forceinline__ float hashf(uint32_t x) {
  x ^= x >> 17; x *= 0xed5ad4bbu; x ^= x >> 11; x *= 0xac4c1b51u;
  x ^= x >> 15; x *= 0x31848babu; x ^= x >> 14;
  return ((float)(x >> 8)) * 1.1920929e-7f - 1.0f;
}

__global__ void seed_kernel(float* __restrict__ Y) {
  uint32_t i = blockIdx.x * 256 + threadIdx.x;
  Y[i] = hashf(i * 2654435761u + 777u);
}

__global__ void colsum_kernel(const float* __restrict__ X, float* __restrict__ s) {
  int col = blockIdx.x * 256 + threadIdx.x;
  int r0 = blockIdx.y * 256;
  float acc = 0.0f;
  for (int r = 0; r < 256; ++r) acc += X[(size_t)(r0 + r) * F_N + col];
  atomicAdd(&s[col], acc);
}

// ---------------- C += partial(X^T X) - [bz==0] s s^T / B ; split-K z=4, lower blocks ----------------
__global__ __launch_bounds__(256) void syrk_kernel(const float* __restrict__ X,
    const float* __restrict__ s, float* __restrict__ C) {
  if (blockIdx.y > blockIdx.x) return;
  __shared__ float As[16][64];
  __shared__ float Bs[16][64];
  const int I = blockIdx.x * 64, J = blockIdx.y * 64;
  const int kbase = blockIdx.z * (B_N / 4);
  const int tid = threadIdx.x;
  const int tx = tid & 15, ty = tid >> 4;
  float acc[4][4] = {};
  for (int kb = 0; kb < B_N / 4; kb += 16) {
    const float4 va = *(const float4*)(&X[(size_t)(kbase + kb + ty) * F_N + I + tx * 4]);
    const float4 vb = *(const float4*)(&X[(size_t)(kbase + kb + ty) * F_N + J + tx * 4]);
    __syncthreads();
    *(float4*)(&As[ty][tx * 4]) = va;
    *(float4*)(&Bs[ty][tx * 4]) = vb;
    __syncthreads();
#pragma unroll
    for (int kk = 0; kk < 16; ++kk) {
      const float4 a = *(const float4*)(&As[kk][ty * 4]);
      const float4 b = *(const float4*)(&Bs[kk][tx * 4]);
      FMA16(acc, a, b)
    }
  }
  const float invB = 1.0f / (float)B_N;
  const bool dos = (blockIdx.z == 0);
#pragma unroll
  for (int u = 0; u < 4; ++u) {
    int gi = I + ty * 4 + u;
    float su = dos ? s[gi] * invB : 0.0f;
#pragma unroll
    for (int v = 0; v < 4; ++v) {
      int gj = J + tx * 4 + v;
      atomicAdd(&C[(size_t)gi * F_N + gj], acc[u][v] - su * s[gj]);
    }
  }
}

// ---------------- mirror lower -> upper, 32x32 LDS transpose tiles ----------------
__global__ __launch_bounds__(256) void mirror_kernel(float* __restrict__ D) {
  const int bi = blockIdx.x, bj = blockIdx.y;
  if (bj > bi) return;
  __shared__ float t[32][33];
  const int r = threadIdx.x >> 5, c = threadIdx.x & 31;
  const int I = bi * 32, J = bj * 32;
#pragma unroll
  for (int rr = r; rr < 32; rr += 8) t[rr][c] = D[(size_t)(I + rr) * F_N + J + c];
  __syncthreads();
  if (bi == bj) {
#pragma unroll
    for (int rr = r; rr < 32; rr += 8) if (c > rr) D[(size_t)(J + rr) * F_N + I + c] = t[c][rr];
  } else {
#pragma unroll
    for (int rr = r; rr < 32; rr += 8) D[(size_t)(J + rr) * F_N + I + c] = t[c][rr];
  }
}

// ---------------- D += scale * partial(A * B^T); split-K z=2, lower blocks ----------------
__global__ __launch_bounds__(256) void gemm_nt_kernel(const float* __restrict__ A,
    const float* __restrict__ B, float* __restrict__ D, float scale) {
  if (blockIdx.y > blockIdx.x) return;
  __shared__ float As[32][68];
  __shared__ float Bs[32][68];
  const int I = blockIdx.x * 64, J = blockIdx.y * 64;
  const int kbase = blockIdx.z * (F_N / 2);
  const int tid = threadIdx.x;
  const int tx = tid & 15, ty = tid >> 4;
  const int lr = tid >> 2, ls = (tid & 3) * 4;
  float acc[4][4] = {};
  for (int kb = 0; kb < F_N / 2; kb += 32) {
    const float4 a0 = *(const float4*)(&A[(size_t)(I + lr) * F_N + kbase + kb + ls]);
    const float4 a1 = *(const float4*)(&A[(size_t)(I + lr) * F_N + kbase + kb + 16 + ls]);
    const float4 b0 = *(const float4*)(&B[(size_t)(J + lr) * F_N + kbase + kb + ls]);
    const float4 b1 = *(const float4*)(&B[(size_t)(J + lr) * F_N + kbase + kb + 16 + ls]);
    __syncthreads();
    As[ls + 0][lr] = a0.x; As[ls + 1][lr] = a0.y; As[ls + 2][lr] = a0.z; As[ls + 3][lr] = a0.w;
    As[16 + ls + 0][lr] = a1.x; As[16 + ls + 1][lr] = a1.y; As[16 + ls + 2][lr] = a1.z; As[16 + ls + 3][lr] = a1.w;
    Bs[ls + 0][lr] = b0.x; Bs[ls + 1][lr] = b0.y; Bs[ls + 2][lr] = b0.z; Bs[ls + 3][lr] = b0.w;
    Bs[16 + ls + 0][lr] = b1.x; Bs[16 + ls + 1][lr] = b1.y; Bs[16 + ls + 2][lr] = b1.z; Bs[16 + ls + 3][lr] = b1.w;
    __syncthreads();
#pragma unroll
    for (int kk = 0; kk < 32; ++kk) {
      const float4 a = *(const float4*)(&As[kk][ty * 4]);
      const float4 b = *(const float4*)(&Bs[kk][tx * 4]);
      FMA16(acc, a, b)
    }
  }
#pragma unroll
  for (int u = 0; u < 4; ++u)
#pragma unroll
    for (int v = 0; v < 4; ++v)
      atomicAdd(&D[(size_t)(I + ty * 4 + u) * F_N + J + tx * 4 + v], acc[u][v] * scale);
}

// ---------------- Yout += M * Yin; split-K z=8 ----------------
__global__ __launch_bounds__(256) void powgemm_kernel(const float* __restrict__ M,
    const float* __restrict__ Yin, float* __restrict__ Yout) {
  __shared__ float Ast[32][68];
  __shared__ float Bs[32][64];
  const int I = blockIdx.x * 64, J = blockIdx.y * 64;
  const int kbase = blockIdx.z * (F_N / 8);
  const int tid = threadIdx.x;
  const int tx = tid & 15, ty = tid >> 4;
  float acc[4][4] = {};
  for (int kb = 0; kb < F_N / 8; kb += 32) {
    int r = tid >> 2, cb = (tid & 3) * 8;
    const float4 a0 = *(const float4*)(&M[(size_t)(I + r) * F_N + kbase + kb + cb]);
    const float4 a1 = *(const float4*)(&M[(size_t)(I + r) * F_N + kbase + kb + cb + 4]);
    const float4 bv0 = *(const float4*)(&Yin[(size_t)(kbase + kb + (tid >> 4)) * K_N + J + (tid & 15) * 4]);
    const float4 bv1 = *(const float4*)(&Yin[(size_t)(kbase + kb + (tid >> 4) + 16) * K_N + J + (tid & 15) * 4]);
    __syncthreads();
    Ast[cb + 0][r] = a0.x; Ast[cb + 1][r] = a0.y; Ast[cb + 2][r] = a0.z; Ast[cb + 3][r] = a0.w;
    Ast[cb + 4][r] = a1.x; Ast[cb + 5][r] = a1.y; Ast[cb + 6][r] = a1.z; Ast[cb + 7][r] = a1.w;
    *(float4*)(&Bs[tid >> 4][(tid & 15) * 4]) = bv0;
    *(float4*)(&Bs[(tid >> 4) + 16][(tid & 15) * 4]) = bv1;
    __syncthreads();
#pragma unroll
    for (int kk = 0; kk < 32; ++kk) {
      const float4 a = *(const float4*)(&Ast[kk][ty * 4]);
      const float4 b = *(const float4*)(&Bs[kk][tx * 4]);
      FMA16(acc, a, b)
    }
  }
#pragma unroll
  for (int u = 0; u < 4; ++u)
#pragma unroll
    for (int v = 0; v < 4; ++v)
      atomicAdd(&Yout[(size_t)(I + ty * 4 + u) * K_N + J + tx * 4 + v], acc[u][v]);
}

// ---------------- G += Y^T Y ; split-K z=16 ----------------
__global__ __launch_bounds__(256) void gram_kernel(const float* __restrict__ Y, float* __restrict__ G) {
  __shared__ float As[16][64];
  __shared__ float Bs[16][64];
  const int I = blockIdx.x * 64, J = blockIdx.y * 64;
  const int k0 = blockIdx.z * (F_N / 16);
  const int tid = threadIdx.x;
  const int tx = tid & 15, ty = tid >> 4;
  float acc[4][4] = {};
  for (int kb = 0; kb < F_N / 16; kb += 16) {
    const float4 va = *(const float4*)(&Y[(size_t)(k0 + kb + ty) * K_N + I + tx * 4]);
    const float4 vb = *(const float4*)(&Y[(size_t)(k0 + kb + ty) * K_N + J + tx * 4]);
    __syncthreads();
    *(float4*)(&As[ty][tx * 4]) = va;
    *(float4*)(&Bs[ty][tx * 4]) = vb;
    __syncthreads();
#pragma unroll
    for (int kk = 0; kk < 16; ++kk) {
      const float4 a = *(const float4*)(&As[kk][ty * 4]);
      const float4 b = *(const float4*)(&Bs[kk][tx * 4]);
      FMA16(acc, a, b)
    }
  }
#pragma unroll
  for (int u = 0; u < 4; ++u)
#pragma unroll
    for (int v = 0; v < 4; ++v)
      atomicAdd(&G[(size_t)(I + ty * 4 + u) * K_N + J + tx * 4 + v], acc[u][v]);
}

// ---------------- 256x256 Cholesky, rank-8 panel blocked, packed-lower LDS ----------------
__global__ __launch_bounds__(256) void chol_kernel(const float* __restrict__ Ain,
    float* __restrict__ Lout, float* __restrict__ invdout, float* __restrict__ logdet) {
  const int b = blockIdx.x;
  const float* A = Ain + (size_t)b * K_N * K_N;
  float* L = Lout + (size_t)b * K_N * K_N;
  const int tid = threadIdx.x;
  const int rb = (tid * (tid + 1)) >> 1;
  __shared__ float T[(K_N * (K_N + 1)) / 2];   // 131.5 KB packed lower
  __shared__ float colp[K_N][9];               // panel L columns, stride 9 breaks conflicts
  __shared__ float sh_invd, sh_ld;
  for (int i = 0; i < K_N; ++i)
    if (tid <= i) T[((i * (i + 1)) >> 1) + tid] = A[(size_t)i * K_N + tid];
  if (tid == 0) sh_ld = 0.f;
  __syncthreads();
  for (int p0 = 0; p0 < K_N; p0 += NB) {
    for (int jj = 0; jj < NB; ++jj) {
      const int j = p0 + jj;
      float t = 0.f;
      if (tid >= j) {
        t = T[rb + j];
        for (int q = 0; q < jj; ++q) t -= colp[tid][q] * colp[j][q];
      }
      float dloc = 0.f;
      if (tid == j) {
        dloc = sqrtf(fmaxf(t, 1e-20f));
        sh_invd = 1.0f / dloc;
        sh_ld += logf(dloc);
      }
      __syncthreads();
      if (tid > j) {
        float cc = t * sh_invd;
        T[rb + j] = cc;
        colp[tid][jj] = cc;
      } else if (tid == j) {
        T[rb + j] = dloc;
        colp[tid][jj] = dloc;
      }
      __syncthreads();
    }
    const int p1 = p0 + NB;
    if (p1 < K_N) {
      const int nr2 = (K_N - p1) >> 1;
      const int M2 = (nr2 * (nr2 + 1)) >> 1;
      for (int e = tid; e < M2; e += 256) {
        int t2 = (int)((sqrtf(8.f * (float)e + 1.f) - 1.f) * 0.5f);
        while (((t2 + 1) * (t2 + 2)) / 2 <= e) ++t2;
        while ((t2 * (t2 + 1)) / 2 > e) --t2;
        const int i0 = p1 + (t2 << 1);
        const int k0 = p1 + ((e - ((t2 * (t2 + 1)) >> 1)) << 1);
        float s00 = 0.f, s01 = 0.f, s10 = 0.f, s11 = 0.f;
#pragma unroll
        for (int q = 0; q < NB; ++q) {
          const float a0 = colp[i0][q], a1 = colp[i0 + 1][q];
          const float b0 = colp[k0][q], b1 = colp[k0 + 1][q];
          s00 += a0 * b0; s01 += a0 * b1; s10 += a1 * b0; s11 += a1 * b1;
        }
        const int rb0 = (i0 * (i0 + 1)) >> 1;
        const int rb1 = ((i0 + 1) * (i0 + 2)) >> 1;
        T[rb0 + k0] -= s00;
        if (i0 != k0) T[rb0 + k0 + 1] -= s01;
        T[rb1 + k0] -= s10;
        T[rb1 + k0 + 1] -= s11;
      }
    }
    __syncthreads();
  }
  if (tid == 0) logdet[b] = 2.0f * sh_ld;
  invdout[(size_t)b * K_N + tid] = 1.0f / T[rb + tid];
  for (int i = 0; i < K_N; ++i)
    if (tid <= i) L[(size_t)i * K_N + tid] = T[((i * (i + 1)) >> 1) + tid];
}

// ---------------- wave-per-row TRSM: Yout * L^T = Yin ----------------
__global__ __launch_bounds__(256) void trsm_rows_kernel(const float* __restrict__ L,
    const float* __restrict__ invd, const float* __restrict__ Yin, float* __restrict__ Yout) {
  const int w = threadIdx.x >> 6, lane = threadIdx.x & 63;
  const int row = blockIdx.x * 4 + w;
  float yv[4];
#pragma unroll
  for (int m = 0; m < 4; ++m) yv[m] = Yin[(size_t)row * K_N + lane + 64 * m];
#pragma unroll
  for (int m = 0; m < 4; ++m) {
    for (int cc = 0; cc < 64; ++cc) {
      const int c = m * 64 + cc;
      const float* Lrow = L + (size_t)c * K_N;
      float yc = __shfl(yv[m], cc);
      float part = 0.f;
#pragma unroll
      for (int mm = 0; mm < m; ++mm) part += yv[mm] * Lrow[lane + 64 * mm];
      if (lane < cc) part += yv[m] * Lrow[lane + 64 * m];
#pragma unroll
      for (int off = 1; off < 64; off <<= 1) part += __shfl_xor(part, off);
      float val = (yc - part) * invd[c];
      if (lane == cc) yv[m] = val;
    }
  }
#pragma unroll
  for (int m = 0; m < 4; ++m) Yout[(size_t)row * K_N + lane + 64 * m] = yv[m];
}

// ---------------- wave-per-column solve L W = I; writes W^T ----------------
__global__ __launch_bounds__(256) void trsm_winv_kernel(const float* __restrict__ Lall,
    const float* __restrict__ invdall, float* __restrict__ Wt) {
  const int w = threadIdx.x >> 6, lane = threadIdx.x & 63;
  const int gw = blockIdx.x * 4 + w;
  const int b = gw >> 8, j = gw & 255;
  const float* L = Lall + (size_t)b * K_N * K_N;
  const float* invd = invdall + (size_t)b * K_N;
  float yv[4];
#pragma unroll
  for (int m = 0; m < 4; ++m) yv[m] = 0.f;
#pragma unroll
  for (int m = 0; m < 4; ++m) {
    for (int cc = 0; cc < 64; ++cc) {
      const int c = m * 64 + cc;
      const float* Lrow = L + (size_t)c * K_N;
      float part = 0.f;
#pragma unroll
      for (int mm = 0; mm < m; ++mm) part += yv[mm] * Lrow[lane + 64 * mm];
      if (lane < cc) part += yv[m] * Lrow[lane + 64 * m];
#pragma unroll
      for (int off = 1; off < 64; off <<= 1) part += __shfl_xor(part, off);
      float val = (((c == j) ? 1.0f : 0.0f) - part) * invd[c];
      if (lane == cc) yv[m] = val;
    }
  }
#pragma unroll
  for (int m = 0; m < 4; ++m) Wt[((size_t)b * K_N + j) * K_N + lane + 64 * m] = yv[m];
}

// ---------------- P += partial(X * Y); split-K z=2 (no centering: cancels in KL) ----------------
__global__ __launch_bounds__(256) void proj_kernel(const float* __restrict__ X,
    const float* __restrict__ Y, float* __restrict__ P) {
  __shared__ float Ast[32][68];
  __shared__ float Bs[32][64];
  const int I = blockIdx.x * 64, J = blockIdx.y * 64;
  const int kbase = blockIdx.z * (F_N / 2);
  const int tid = threadIdx.x;
  const int tx = tid & 15, ty = tid >> 4;
  float acc[4][4] = {};
  for (int kb = 0; kb < F_N / 2; kb += 32) {
    {
      int r = tid >> 2, cb = (tid & 3) * 8;
      const float4 a0 = *(const float4*)(&X[(size_t)(I + r) * F_N + kbase + kb + cb]);
      const float4 a1 = *(const float4*)(&X[(size_t)(I + r) * F_N + kbase + kb + cb + 4]);
      const float4 bv0 = *(const float4*)(&Y[(size_t)(kbase + kb + (tid >> 4)) * K_N + J + (tid & 15) * 4]);
      const float4 bv1 = *(const float4*)(&Y[(size_t)(kbase + kb + (tid >> 4) + 16) * K_N + J + (tid & 15) * 4]);
      __syncthreads();
      Ast[cb + 0][r] = a0.x; Ast[cb + 1][r] = a0.y; Ast[cb + 2][r] = a0.z; Ast[cb + 3][r] = a0.w;
      Ast[cb + 4][r] = a1.x; Ast[cb + 5][r] = a1.y; Ast[cb + 6][r] = a1.z; Ast[cb + 7][r] = a1.w;
      *(float4*)(&Bs[tid >> 4][(tid & 15) * 4]) = bv0;
      *(float4*)(&Bs[(tid >> 4) + 16][(tid & 15) * 4]) = bv1;
    }
    __syncthreads();
#pragma unroll
    for (int kk = 0; kk < 32; ++kk) {
      const float4 a = *(const float4*)(&Ast[kk][ty * 4]);
      const float4 b = *(const float4*)(&Bs[kk][tx * 4]);
      FMA16(acc, a, b)
    }
  }
#pragma unroll
  for (int u = 0; u < 4; ++u)
#pragma unroll
    for (int v = 0; v < 4; ++v)
      atomicAdd(&P[(size_t)(I + ty * 4 + u) * K_N + J + tx * 4 + v], acc[u][v]);
}

__global__ void counts_kernel(const int* __restrict__ labels, int* __restrict__ counts) {
  __shared__ int c[L_N];
  int tid = threadIdx.x;
  if (tid < L_N) c[tid] = 0;
  __syncthreads();
  int lab = labels[blockIdx.x * 256 + tid];
  atomicAdd(&c[lab], 1);
  __syncthreads();
  if (tid < L_N) atomicAdd(&counts[tid], c[tid]);
}

__global__ void musum_kernel(const int* __restrict__ labels, const float* __restrict__ P,
                             float* __restrict__ musum) {
  __shared__ float m[L_N][K_N];
  int tid = threadIdx.x;
#pragma unroll
  for (int l = 0; l < L_N; ++l) m[l][tid] = 0.0f;
  __syncthreads();
  int base = blockIdx.x * 256;
  for (int r = 0; r < 256; ++r) {
    int lab = labels[base + r];
    m[lab][tid] += P[(size_t)(base + r) * K_N + tid];
  }
  __syncthreads();
#pragma unroll
  for (int l = 0; l < L_N; ++l) atomicAdd(&musum[l * K_N + tid], m[l][tid]);
}

__global__ void compact_kernel(const int* __restrict__ labels, int* __restrict__ idx) {
  const int l = blockIdx.x;
  const int tid = threadIdx.x;
  __shared__ int sc[256];
  __shared__ int s_off;
  if (tid == 0) s_off = 0;
  __syncthreads();
  for (int base = 0; base < B_N; base += 256) {
    int match = (labels[base + tid] == l) ? 1 : 0;
    sc[tid] = match;
    __syncthreads();
    for (int st = 1; st < 256; st <<= 1) {
      int v = (tid >= st) ? sc[tid - st] : 0;
      __syncthreads();
      sc[tid] += v;
      __syncthreads();
    }
    if (match) idx[l * 2048 + s_off + sc[tid] - 1] = base + tid;
    __syncthreads();
    if (tid == 0) s_off += sc[255];
    __syncthreads();
  }
}

__global__ __launch_bounds__(256) void scatter_kernel(const float* __restrict__ P,
    const int* __restrict__ idx, const int* __restrict__ counts, float* __restrict__ S) {
  const int Ib = blockIdx.y >> 2, Jb = blockIdx.y & 3;
  if (Jb > Ib) return;
  __shared__ float As[32][64];
  __shared__ float Bs[32][64];
  const int l = blockIdx.x;
  const int I = Ib * 64, J = Jb * 64;
  const int cnt = counts[l];
  const int tid = threadIdx.x;
  const int tx = tid & 15, ty = tid >> 4;
  float acc[4][4] = {};
  for (int chunk = 0; chunk < cnt; chunk += 32) {
#pragma unroll
    for (int e = 0; e < 2; ++e) {
      int r = (tid >> 4) + e * 16;
      int rr = chunk + r;
      float4 va = {0.f, 0.f, 0.f, 0.f}, vb = {0.f, 0.f, 0.f, 0.f};
      if (rr < cnt) {
        int row = idx[l * 2048 + rr];
        va = *(const float4*)(&P[(size_t)row * K_N + I + (tid & 15) * 4]);
        vb = *(const float4*)(&P[(size_t)row * K_N + J + (tid & 15) * 4]);
      }
      __syncthreads();
      *(float4*)(&As[r][(tid & 15) * 4]) = va;
      *(float4*)(&Bs[r][(tid & 15) * 4]) = vb;
    }
    __syncthreads();
#pragma unroll
    for (int kk = 0; kk < 32; ++kk) {
      const float4 a = *(const float4*)(&As[kk][ty * 4]);
      const float4 b = *(const float4*)(&Bs[kk][tx * 4]);
      FMA16(acc, a, b)
    }
  }
  const bool mirror = (Ib != Jb);
#pragma unroll
  for (int u = 0; u < 4; ++u)
#pragma unroll
    for (int v = 0; v < 4; ++v) {
      S[((size_t)l * K_N + I + ty * 4 + u) * K_N + J + tx * 4 + v] = acc[u][v];
      if (mirror) S[((size_t)l * K_N + J + tx * 4 + v) * K_N + I + ty * 4 + u] = acc[u][v];
    }
}

__global__ void sigbuild_kernel(float* __restrict__ S, float* __restrict__ CH,
    const float* __restrict__ musum, const int* __restrict__ counts) {
  const int l = blockIdx.x, i = blockIdx.y, j = threadIdx.x;
  const float cf = fmaxf((float)counts[l], 1.0f);
  const float inv = 1.0f / cf;
  const float mui = musum[l * K_N + i] * inv;
  const float muj = musum[l * K_N + j] * inv;
  size_t o = ((size_t)l * K_N + i) * K_N + j;
  float v = S[o] * inv - mui * muj + ((i == j) ? SIGMA_F : 0.0f);
  S[o] = v;
  CH[o] = v;
}

__global__ __launch_bounds__(256) void sinv_nt_kernel(const float* __restrict__ Wt, float* __restrict__ V) {
  if (blockIdx.y > blockIdx.x) return;
  __shared__ float As[32][68];
  __shared__ float Bs[32][68];
  const int b = blockIdx.z;
  const float* Wb = Wt + (size_t)b * K_N * K_N;
  const int I = blockIdx.x * 64, J = blockIdx.y * 64;
  const int tid = threadIdx.x;
  const int tx = tid & 15, ty = tid >> 4;
  const int lr = tid >> 2, ls = (tid & 3) * 4;
  float acc[4][4] = {};
  for (int kb = 0; kb < K_N; kb += 32) {
    const float4 a0 = *(const float4*)(&Wb[(size_t)(I + lr) * K_N + kb + ls]);
    const float4 a1 = *(const float4*)(&Wb[(size_t)(I + lr) * K_N + kb + 16 + ls]);
    const float4 b0 = *(const float4*)(&Wb[(size_t)(J + lr) * K_N + kb + ls]);
    const float4 b1 = *(const float4*)(&Wb[(size_t)(J + lr) * K_N + kb + 16 + ls]);
    __syncthreads();
    As[ls + 0][lr] = a0.x; As[ls + 1][lr] = a0.y; As[ls + 2][lr] = a0.z; As[ls + 3][lr] = a0.w;
    As[16 + ls + 0][lr] = a1.x; As[16 + ls + 1][lr] = a1.y; As[16 + ls + 2][lr] = a1.z; As[16 + ls + 3][lr] = a1.w;
    Bs[ls + 0][lr] = b0.x; Bs[ls + 1][lr] = b0.y; Bs[ls + 2][lr] = b0.z; Bs[ls + 3][lr] = b0.w;
    Bs[16 + ls + 0][lr] = b1.x; Bs[16 + ls + 1][lr] = b1.y; Bs[16 + ls + 2][lr] = b1.z; Bs[16 + ls + 3][lr] = b1.w;
    __syncthreads();
#pragma unroll
    for (int kk = 0; kk < 32; ++kk) {
      const float4 a = *(const float4*)(&As[kk][ty * 4]);
      const float4 b = *(const float4*)(&Bs[kk][tx * 4]);
      FMA16(acc, a, b)
    }
  }
  const bool mirror = (blockIdx.x != blockIdx.y);
#pragma unroll
  for (int u = 0; u < 4; ++u)
#pragma unroll
    for (int v = 0; v < 4; ++v) {
      V[((size_t)b * K_N + I + ty * 4 + u) * K_N + J + tx * 4 + v] = acc[u][v];
      if (mirror) V[((size_t)b * K_N + J + tx * 4 + v) * K_N + I + ty * 4 + u] = acc[u][v];
    }
}

__global__ void klpairs_kernel(const float* __restrict__ SIG, const float* __restrict__ SINV,
    const float* __restrict__ musum, const int* __restrict__ counts,
    const float* __restrict__ logdet, float* __restrict__ klbuf) {
  const int j = blockIdx.x, i = blockIdx.y;
  const int tid = threadIdx.x;
  if (i == j) { if (tid == 0) klbuf[i * L_N + j] = 0.0f; return; }
  const float* Si = SIG + (size_t)i * K_N * K_N;
  const float* Vj = SINV + (size_t)j * K_N * K_N;
  const float ci = fmaxf((float)counts[i], 1.0f);
  const float cj = fmaxf((float)counts[j], 1.0f);
  __shared__ float diff[K_N];
  diff[tid] = musum[i * K_N + tid] / ci - musum[j * K_N + tid] / cj;
  float tr = 0.0f;
  for (int e = tid; e < K_N * K_N; e += 256) tr += Vj[e] * Si[e];
  __syncthreads();
  float tmp = 0.0f;
  for (int b2 = 0; b2 < K_N; ++b2) tmp += Vj[(size_t)b2 * K_N + tid] * diff[b2];
  float mah = tmp * diff[tid];
  __shared__ float red[256];
  red[tid] = tr + mah;
  __syncthreads();
  for (int st = 128; st > 0; st >>= 1) {
    if (tid < st) red[tid] += red[tid + st];
    __syncthreads();
  }
  if (tid == 0) {
    float kl = 0.5f * (logdet[j] - logdet[i] - (float)K_N + red[0]);
    klbuf[i * L_N + j] = (float)counts[i] * (float)counts[j] * kl;
  }
}

__global__ void final_kernel(const float* __restrict__ klbuf, float* __restrict__ out) {
  __shared__ float red[128];
  int tid = threadIdx.x;
  red[tid] = (tid < L_N * L_N) ? klbuf[tid] : 0.0f;
  __syncthreads();
  for (int st = 64; st > 0; st >>= 1) {
    if (tid < st) red[tid] += red[tid + st];
    __syncthreads();
  }
  if (tid == 0) out[0] = red[0] / 5.49755813888e11f;
}

extern "C" void kernel_launch(void* const* d_in, const int* in_sizes, int n_in,
                              void* d_out, int out_size, void* d_ws, size_t ws_size,
                              hipStream_t stream) {
  (void)in_sizes; (void)n_in; (void)out_size; (void)ws_size;
  const float* X = (const float*)d_in[0];
  const int* labels = (const int*)d_in[1];
  float* out = (float*)d_out;

  float* w = (float*)d_ws;
  size_t off = 0;
  auto alloc = [&](size_t n) { float* p = w + off; off += (n + 63) & ~(size_t)63; return p; };
  float* C    = alloc((size_t)F_N * F_N);      // later reused as C4
  float* C2   = alloc((size_t)F_N * F_N);
  float* Y0   = alloc((size_t)F_N * K_N);
  float* Y1   = alloc((size_t)F_N * K_N);
  float* P    = alloc((size_t)B_N * K_N);
  float* S    = alloc((size_t)L_N * K_N * K_N);
  float* CH   = alloc((size_t)L_N * K_N * K_N); // later reused as SINV
  float* LL   = alloc((size_t)L_N * K_N * K_N);
  float* Wt   = alloc((size_t)L_N * K_N * K_N);
  float* G2   = alloc((size_t)K_N * K_N);
  float* LQ   = alloc((size_t)K_N * K_N);
  float* svec = alloc(F_N);
  float* musum = alloc(L_N * K_N);
  float* logdet = alloc(64);
  float* klbuf = alloc(128);
  float* ldq = alloc(64);
  float* invdQ = alloc(K_N);
  float* invdL = alloc(L_N * K_N);
  int* counts = (int*)alloc(64);
  int* idx = (int*)alloc(L_N * 2048);
  float* C4 = C;
  float* SINV = CH;

  hipMemsetAsync(svec, 0, F_N * 4, stream);
  hipMemsetAsync(counts, 0, 64 * 4, stream);
  hipMemsetAsync(musum, 0, L_N * K_N * 4, stream);

  colsum_kernel<<<dim3(F_N / 256, B_N / 256), 256, 0, stream>>>(X, svec);
  hipMemsetAsync(C, 0, (size_t)F_N * F_N * 4, stream);
  syrk_kernel<<<dim3(F_N / 64, F_N / 64, 4), 256, 0, stream>>>(X, svec, C);
  mirror_kernel<<<dim3(F_N / 32, F_N / 32), 256, 0, stream>>>(C);
  hipMemsetAsync(C2, 0, (size_t)F_N * F_N * 4, stream);
  gemm_nt_kernel<<<dim3(F_N / 64, F_N / 64, 2), 256, 0, stream>>>(C, C, C2, (float)SC2);
  mirror_kernel<<<dim3(F_N / 32, F_N / 32), 256, 0, stream>>>(C2);
  hipMemsetAsync(C4, 0, (size_t)F_N * F_N * 4, stream);   // C dead after C2 built
  gemm_nt_kernel<<<dim3(F_N / 64, F_N / 64, 2), 256, 0, stream>>>(C2, C2, C4, 1.0f);
  mirror_kernel<<<dim3(F_N / 32, F_N / 32), 256, 0, stream>>>(C4);
  seed_kernel<<<(F_N * K_N) / 256, 256, 0, stream>>>(Y0);

  float* Yc = Y0; float* Yn = Y1;
  auto do_apply = [&](const float* M) {
    hipMemsetAsync(Yn, 0, (size_t)F_N * K_N * 4, stream);
    powgemm_kernel<<<dim3(F_N / 64, K_N / 64, 8), 256, 0, stream>>>(M, Yc, Yn);
    float* t = Yc; Yc = Yn; Yn = t;
  };
  auto do_qr = [&]() {
    hipMemsetAsync(G2, 0, (size_t)K_N * K_N * 4, stream);
    gram_kernel<<<dim3(4, 4, 16), 256, 0, stream>>>(Yc, G2);
    chol_kernel<<<1, 256, 0, stream>>>(G2, LQ, invdQ, ldq);
    trsm_rows_kernel<<<F_N / 4, 256, 0, stream>>>(LQ, invdQ, Yc, Yn);
    float* t = Yc; Yc = Yn; Yn = t;
  };

  // lambda^42 = C4 x10 + C2 x1. Orths at t=4, 24, 42 (+polish = CholQR2) — validated R5.
  do_apply(C4);                                 // t=4
  do_qr();
  for (int a = 0; a < 5; ++a) do_apply(C4);     // t=24
  do_qr();
  for (int a = 0; a < 4; ++a) do_apply(C4);     // t=40
  do_apply(C2);                                 // t=42
  do_qr();
  do_qr();                                      // polish

  hipMemsetAsync(P, 0, (size_t)B_N * K_N * 4, stream);
  proj_kernel<<<dim3(B_N / 64, K_N / 64, 2), 256, 0, stream>>>(X, Yc, P);
  counts_kernel<<<B_N / 256, 256, 0, stream>>>(labels, counts);
  musum_kernel<<<B_N / 256, 256, 0, stream>>>(labels, P, musum);
  compact_kernel<<<L_N, 256, 0, stream>>>(labels, idx);
  scatter_kernel<<<dim3(L_N, 16), 256, 0, stream>>>(P, idx, counts, S);
  sigbuild_kernel<<<dim3(L_N, K_N), 256, 0, stream>>>(S, CH, musum, counts);
  chol_kernel<<<L_N, 256, 0, stream>>>(CH, LL, invdL, logdet);
  trsm_winv_kernel<<<(L_N * K_N) / 4, 256, 0, stream>>>(LL, invdL, Wt);
  sinv_nt_kernel<<<dim3(4, 4, L_N), 256, 0, stream>>>(Wt, SINV);
  klpairs_kernel<<<dim3(L_N, L_N), 256, 0, stream>>>(S, SINV, musum, counts, logdet, klbuf);
  final_kernel<<<1, 128, 0, stream>>>(klbuf, out);
}